// Round 5
// baseline (12013.327 us; speedup 1.0000x reference)
//
#include <hip/hip_runtime.h>
#include <math.h>

typedef _Float16 f16;
typedef _Float16 f16x8 __attribute__((ext_vector_type(8)));
typedef float f32x4 __attribute__((ext_vector_type(4)));
union HU { f16 h; unsigned short u; };

#define NT 512
#define NBLK 160            // 64 g2 + 32 g1 + 64 at
#define ABE 69632           // f16 per parity buffer (64*1088)
#define OUTG_OFF 69632      // float offset in ws
#define LOSS_OFF 77824
#define FLAG_OFF 78080      // uint offset
#define DYN_LDS 132096

// ---- coherent (cross-XCD) access primitives: plain vmcnt-counted loads/stores
// that bypass L1/L2 (sc0 sc1) -> serviced at the coherent point (L3). ----
__device__ __forceinline__ f16x8 cld16(const void* p) {
  f16x8 r;
  asm volatile("global_load_dwordx4 %0, %1, off sc0 sc1" : "=v"(r) : "v"(p) : "memory");
  return r;
}
__device__ __forceinline__ uint4 cld128u(const void* p) {
  uint4 r;
  asm volatile("global_load_dwordx4 %0, %1, off sc0 sc1"
               : "=v"(r) : "v"(p) : "memory");
  return r;
}
__device__ __forceinline__ unsigned cld32u(const void* p) {
  unsigned r;
  asm volatile("global_load_dword %0, %1, off sc0 sc1" : "=v"(r) : "v"(p) : "memory");
  return r;
}
__device__ __forceinline__ void cst32(void* p, unsigned v) {
  asm volatile("global_store_dword %0, %1, off sc0 sc1" :: "v"(p), "v"(v) : "memory");
}
#define VMWAIT() do { asm volatile("s_waitcnt vmcnt(0)" ::: "memory"); \
                      __builtin_amdgcn_sched_barrier(0); } while (0)

__device__ __forceinline__ float sigm(float v){ return 1.f/(1.f+expf(-v)); }

// flag barrier: store own slot, wave0 polls all 160 slots (40 lanes x dwordx4)
__device__ __forceinline__ void gbar(unsigned* flags, unsigned target) {
  asm volatile("s_waitcnt vmcnt(0)" ::: "memory");
  __syncthreads();
  if (threadIdx.x == 0) cst32(flags + blockIdx.x, target);
  if (threadIdx.x < 64) {
    bool ok;
    do {
      uint4 vv; vv.x = vv.y = vv.z = vv.w = target;
      if (threadIdx.x < 40) {
        vv = cld128u(flags + threadIdx.x * 4);
        asm volatile("s_waitcnt vmcnt(0)" ::: "memory");
      }
      ok = (vv.x >= target) && (vv.y >= target) && (vv.z >= target) && (vv.w >= target);
    } while (!__all(ok));
  }
  __syncthreads();
}

__device__ __forceinline__ float mix_loss(const float* so, const float* yl, int t, int m) {
  float y1 = yl[t*3+0], y2 = yl[t*3+1], ys = yl[t*3+2];
  float ph = (m < 20) ? so[1+m] : -1e30f;
  float mx = ph;
  #pragma unroll
  for (int d = 16; d >= 1; d >>= 1) mx = fmaxf(mx, __shfl_xor(mx, d));
  float pe = (m < 20) ? expf(ph - mx) : 0.f;
  float ps = pe;
  #pragma unroll
  for (int d = 16; d >= 1; d >>= 1) ps += __shfl_xor(ps, d);
  float contrib = 0.f;
  if (m < 20) {
    float mu1 = so[21+m], mu2 = so[41+m];
    float s1 = expf(so[61+m]), s2 = expf(so[81+m]);
    float rh = tanhf(so[101+m]);
    float d1 = (y1-mu1)/s1, d2 = (y2-mu2)/s2;
    float omr = 1.f - rh*rh;
    float z = d1*d1 + d2*d2 - 2.f*rh*d1*d2;
    float ga = expf(-z/(2.f*omr)) / (6.283185307179586f * s1 * s2 * sqrtf(omr));
    contrib = (pe/ps)*ga;
  }
  float gs = contrib;
  #pragma unroll
  for (int d = 16; d >= 1; d >>= 1) gs += __shfl_xor(gs, d);
  float lg = -logf(gs + 1e-20f);
  float e = 1.f/(1.f + expf(so[0]));
  float lb = -logf((e + 1e-20f)*ys + (1.f - e + 1e-20f)*(1.f - ys));
  return lg + lb;
}

__global__ __launch_bounds__(256) void k_init(float* ws) {
  unsigned* w0 = (unsigned*)ws;
  unsigned* wb = (unsigned*)ws + FLAG_OFF;
  int idx = blockIdx.x*256 + threadIdx.x;
  int str = gridDim.x*256;
  for (int e = idx; e < ABE; e += str) w0[e] = 0u;   // both A parity buffers
  if (idx < NBLK) wb[idx] = 0u;                      // barrier flags
}

__global__ __launch_bounds__(NT, 1) void kmain(
    const float* __restrict__ x, const float* __restrict__ y, const float* __restrict__ cvec,
    const float* __restrict__ Wih1, const float* __restrict__ Whh1,
    const float* __restrict__ bih1, const float* __restrict__ bhh1,
    const float* __restrict__ Wih2, const float* __restrict__ Whh2,
    const float* __restrict__ bih2, const float* __restrict__ bhh2,
    const float* __restrict__ Wk, const float* __restrict__ bk,
    const float* __restrict__ Wo, const float* __restrict__ bo,
    float* __restrict__ out, float* __restrict__ ws)
{
  extern __shared__ char dsm[];
  const int blk = blockIdx.x, tid = threadIdx.x;
  const int wv = tid >> 6, l = tid & 63;

  f16* AB = (f16*)ws;
  float* outg  = ws + OUTG_OFF;
  float* lossg = ws + LOSS_OFF;
  unsigned* flags = (unsigned*)ws + FLAG_OFF;

  float lreg = 0.f;

  // ---------------- role init ----------------
  if (blk < 64) {
    // gates2 block: dims blk*8..+8 ; frag LDS [2 nt][34 j][64 l][8]
    f16* wf2 = (f16*)dsm;
    for (int f = tid; f < 2*34*64; f += NT) {
      int nt = f / (34*64), rem = f - nt*34*64, j = rem >> 6, lf = rem & 63;
      int nrow = nt*16 + (lf & 15);
      int R = (nrow >> 3)*512 + blk*8 + (nrow & 7);
      int kbase = j*32 + (lf >> 4)*8;
      #pragma unroll
      for (int e = 0; e < 8; ++e) {
        int k = kbase + e;
        float v = 0.f;
        if (k >= 4 && k < 58)        v = Wih2[R*569 + 515 + (k-4)];   // w
        else if (k >= 58 && k < 61)  v = Wih2[R*569 + (k-58)];        // xB
        else if (k >= 64 && k < 576) v = Wih2[R*569 + 3 + (k-64)];    // h1
        else if (k >= 576)           v = Whh2[R*512 + (k-576)];       // h2
        wf2[f*8 + e] = (f16)v;
      }
    }
  } else if (blk < 96) {
    const int g1i = blk - 64;
    f16* wf1  = (f16*)dsm;                    // [4 nt][18 j][64][8]
    f16* wofr = (f16*)(dsm + 73728);          // [16 j][64][8]
    for (int f = tid; f < 4*18*64; f += NT) {
      int nt = f / (18*64), rem = f - nt*18*64, j = rem >> 6, lf = rem & 63;
      int nrow = nt*16 + (lf & 15);
      int R = (nrow >> 4)*512 + g1i*16 + (nrow & 15);
      int kbase = j*32 + (lf >> 4)*8;
      #pragma unroll
      for (int e = 0; e < 8; ++e) {
        int k = kbase + e;
        float v = 0.f;
        if (k < 3)                   v = Wih1[R*57 + k];              // xA
        else if (k >= 4 && k < 58)   v = Wih1[R*57 + 3 + (k-4)];      // w
        else if (k >= 64 && k < 576) v = Whh1[R*512 + (k-64)];        // h1
        wf1[f*8 + e] = (f16)v;
      }
    }
    for (int f = tid; f < 16*64; f += NT) {
      int j = f >> 6, lf = f & 63;
      int nrow = lf & 15, row = g1i*4 + nrow;
      int kbase = j*32 + (lf >> 4)*8;
      #pragma unroll
      for (int e = 0; e < 8; ++e) {
        float v = (nrow < 4 && row < 121) ? Wo[row*512 + kbase + e] : 0.f;
        wofr[f*8 + e] = (f16)v;
      }
    }
  } else {
    const int b = blk - 96;
    f16*   wk  = (f16*)dsm;                  // [30][520]
    float* cv  = (float*)(dsm + 31200);
    float* xl  = (float*)(dsm + 45024);
    float* yl  = (float*)(dsm + 52224);
    for (int e = tid; e < 30*512; e += NT) { int j = e >> 9, k = e & 511; wk[j*520 + k] = (f16)Wk[e]; }
    for (int e = tid; e < 3456; e += NT) cv[e] = cvec[b*3456 + e];
    for (int e = tid; e < 1800; e += NT) { xl[e] = x[b*1800+e]; yl[e] = y[b*1800+e]; }
    float* kap = (float*)(dsm + 61152);
    if (tid < 10) kap[tid] = 0.f;
    __syncthreads();
    if (tid == 0) {   // stage xA(0) into parity-0
      HU h0, h1u, h2u;
      h0.h = (f16)xl[0]; h1u.h = (f16)xl[1]; h2u.h = (f16)xl[2];
      cst32((unsigned*)AB + (b*1088 >> 1),       (unsigned)h0.u | ((unsigned)h1u.u << 16));
      cst32((unsigned*)AB + ((b*1088 + 2) >> 1), (unsigned)h2u.u);
    }
  }

  // biases into registers
  float bias_g[4] = {0,0,0,0}, bias1a[4] = {0,0,0,0}, bias1b[4] = {0,0,0,0};
  float borow = 0.f;
  float c_st = 0.f, c1a = 0.f, c1b = 0.f;
  if (blk < 64) {
    int pr = tid & 7;
    #pragma unroll
    for (int g = 0; g < 4; ++g) {
      int R = g*512 + blk*8 + pr;
      bias_g[g] = bih2[R] + bhh2[R];
    }
  } else if (blk < 96) {
    int g1i = blk - 64, pr = tid & 7;
    #pragma unroll
    for (int g = 0; g < 4; ++g) {
      int Ra = g*512 + g1i*16 + 2*pr, Rb = Ra + 1;
      bias1a[g] = bih1[Ra] + bhh1[Ra];
      bias1b[g] = bih1[Rb] + bhh1[Rb];
    }
    int r = tid >> 6;
    if (r < 4) { int row = g1i*4 + r; borow = (row < 121) ? bo[row] : 0.f; }
  }

  gbar(flags, 1);

  // ---------------- main recurrence ----------------
  for (int i = 0; i <= 601; ++i) {
    const f16* __restrict__ Acur = AB + (i & 1)*ABE;
    f16* __restrict__ Anxt = AB + ((i & 1)^1)*ABE;
    unsigned* AnxtW = (unsigned*)Anxt;

    // ============ Phase A ============
    if (blk < 64) {
      if (i >= 1 && i <= 600) {
        f16* wf2 = (f16*)dsm;
        float* part2 = (float*)(dsm + 69632);   // [2][64][33]
        const int mt = wv & 3, kh = wv >> 2;
        const int mA = mt*16 + (l & 15);
        const int kb = (l >> 4)*8;
        const f16* Ap = Acur + mA*1088;
        f32x4 acc0 = {0,0,0,0}, acc1 = {0,0,0,0};
        f16x8 fr[17];
        #pragma unroll
        for (int jj = 0; jj < 17; ++jj) {
          int j = kh*17 + jj;
          fr[jj] = cld16(Ap + j*32 + kb);
        }
        VMWAIT();
        #pragma unroll
        for (int jj = 0; jj < 17; ++jj) {
          int j = kh*17 + jj;
          f16x8 b0 = *(const f16x8*)&wf2[((0*34 + j)*64 + l)*8];
          f16x8 b1 = *(const f16x8*)&wf2[((1*34 + j)*64 + l)*8];
          acc0 = __builtin_amdgcn_mfma_f32_16x16x32_f16(fr[jj], b0, acc0, 0, 0, 0);
          acc1 = __builtin_amdgcn_mfma_f32_16x16x32_f16(fr[jj], b1, acc1, 0, 0, 0);
        }
        #pragma unroll
        for (int r = 0; r < 4; ++r) {
          int m = mt*16 + (l>>4)*4 + r;
          part2[(kh*64 + m)*33 + (l & 15)]      = acc0[r];
          part2[(kh*64 + m)*33 + 16 + (l & 15)] = acc1[r];
        }
        __syncthreads();
        {
          int b_ = tid >> 3, pr = tid & 7;
          const float* p0 = &part2[(0*64 + b_)*33];
          const float* p1 = &part2[(1*64 + b_)*33];
          float gi_ = p0[0*8+pr] + p1[0*8+pr] + bias_g[0];
          float gf_ = p0[1*8+pr] + p1[1*8+pr] + bias_g[1];
          float gg_ = p0[2*8+pr] + p1[2*8+pr] + bias_g[2];
          float go_ = p0[3*8+pr] + p1[3*8+pr] + bias_g[3];
          float ig = sigm(gi_), fg = sigm(gf_), gg2 = tanhf(gg_), og = sigm(go_);
          c_st = fg*c_st + ig*gg2;
          HU hu; hu.h = (f16)(og * tanhf(c_st));
          unsigned myv = hu.u;
          unsigned other = (unsigned)__shfl_xor((int)myv, 1);
          if ((pr & 1) == 0)
            cst32(AnxtW + ((b_*1088 + 576 + blk*8 + pr) >> 1), myv | (other << 16));
        }
      }
    } else if (blk < 96) {
      const int g1i = blk - 64;
      f16* wf1  = (f16*)dsm;
      f16* wofr = (f16*)(dsm + 73728);
      float* part1 = (float*)(dsm + 90112);    // [2][64][65]
      float* partp = (float*)(dsm + 123392);   // [2][64][17]
      bool do_g1 = (i <= 599), do_pr = (i >= 2);
      const int mt = wv & 3, kh = wv >> 2;
      const int mA = mt*16 + (l & 15);
      const int kb = (l >> 4)*8;
      f16x8 fr1[9], frp[8];
      if (do_g1) {
        const f16* Ap = Acur + mA*1088;
        #pragma unroll
        for (int jj = 0; jj < 9; ++jj) {
          int j = kh*9 + jj;
          fr1[jj] = cld16(Ap + j*32 + kb);
        }
      }
      if (do_pr) {
        const f16* Ap = Acur + mA*1088 + 576;
        #pragma unroll
        for (int jj = 0; jj < 8; ++jj) {
          int j = kh*8 + jj;
          frp[jj] = cld16(Ap + j*32 + kb);
        }
      }
      VMWAIT();
      if (do_g1) {
        f32x4 acc[4];
        #pragma unroll
        for (int nt = 0; nt < 4; ++nt) acc[nt] = (f32x4){0,0,0,0};
        #pragma unroll
        for (int jj = 0; jj < 9; ++jj) {
          int j = kh*9 + jj;
          #pragma unroll
          for (int nt = 0; nt < 4; ++nt) {
            f16x8 bf = *(const f16x8*)&wf1[((nt*18 + j)*64 + l)*8];
            acc[nt] = __builtin_amdgcn_mfma_f32_16x16x32_f16(fr1[jj], bf, acc[nt], 0, 0, 0);
          }
        }
        #pragma unroll
        for (int nt = 0; nt < 4; ++nt)
          #pragma unroll
          for (int r = 0; r < 4; ++r) {
            int m = mt*16 + (l>>4)*4 + r;
            part1[(kh*64 + m)*65 + nt*16 + (l & 15)] = acc[nt][r];
          }
      }
      if (do_pr) {
        f32x4 accp = {0,0,0,0};
        #pragma unroll
        for (int jj = 0; jj < 8; ++jj) {
          int j = kh*8 + jj;
          f16x8 bf = *(const f16x8*)&wofr[(j*64 + l)*8];
          accp = __builtin_amdgcn_mfma_f32_16x16x32_f16(frp[jj], bf, accp, 0, 0, 0);
        }
        #pragma unroll
        for (int r = 0; r < 4; ++r) {
          int m = mt*16 + (l>>4)*4 + r;
          partp[(kh*64 + m)*17 + (l & 15)] = accp[r];
        }
      }
      if (do_g1 || do_pr) __syncthreads();
      if (do_g1) {
        int b_ = tid >> 3, pr = tid & 7;
        const float* p0 = &part1[(0*64 + b_)*65];
        const float* p1 = &part1[(1*64 + b_)*65];
        float giA = p0[0*16+2*pr] + p1[0*16+2*pr] + bias1a[0];
        float gfA = p0[1*16+2*pr] + p1[1*16+2*pr] + bias1a[1];
        float ggA = p0[2*16+2*pr] + p1[2*16+2*pr] + bias1a[2];
        float goA = p0[3*16+2*pr] + p1[3*16+2*pr] + bias1a[3];
        c1a = sigm(gfA)*c1a + sigm(giA)*tanhf(ggA);
        float hA = sigm(goA) * tanhf(c1a);
        float giB = p0[0*16+2*pr+1] + p1[0*16+2*pr+1] + bias1b[0];
        float gfB = p0[1*16+2*pr+1] + p1[1*16+2*pr+1] + bias1b[1];
        float ggB = p0[2*16+2*pr+1] + p1[2*16+2*pr+1] + bias1b[2];
        float goB = p0[3*16+2*pr+1] + p1[3*16+2*pr+1] + bias1b[3];
        c1b = sigm(gfB)*c1b + sigm(giB)*tanhf(ggB);
        float hB = sigm(goB) * tanhf(c1b);
        HU ua, ub; ua.h = (f16)hA; ub.h = (f16)hB;
        cst32(AnxtW + ((b_*1088 + 64 + g1i*16 + 2*pr) >> 1),
              (unsigned)ua.u | ((unsigned)ub.u << 16));
      }
      if (do_pr && tid < 256) {
        int b_ = tid & 63, r = tid >> 6;
        int row = g1i*4 + r;
        if (row < 121) {
          float v = partp[(0*64 + b_)*17 + r] + partp[(1*64 + b_)*17 + r] + borow;
          unsigned uu; __builtin_memcpy(&uu, &v, 4);
          cst32((unsigned*)outg + b_*128 + row, uu);
        }
      }
    }
    gbar(flags, 2 + 2*i);

    // ============ Phase B ============
    if (blk >= 96) {
      const int b = blk - 96;
      f16*   wk   = (f16*)dsm;
      float* cv   = (float*)(dsm + 31200);
      float* xl   = (float*)(dsm + 45024);
      float* yl   = (float*)(dsm + 52224);
      f16*   h1h  = (f16*)(dsm + 59424);
      float* so   = (float*)(dsm + 60448);
      float* skg  = (float*)(dsm + 60944);
      float* sal  = (float*)(dsm + 61072);
      float* sbe  = (float*)(dsm + 61112);
      float* kap  = (float*)(dsm + 61152);
      float* sphi = (float*)(dsm + 61192);
      float* wtmp = (float*)(dsm + 61448);
      if (i <= 599) {
        if (tid < 64) {
          f16x8 hv = cld16(Anxt + b*1088 + 64 + tid*8);
          asm volatile("s_waitcnt vmcnt(0)" ::: "memory");
          *(f16x8*)&h1h[tid*8] = hv;
        }
        __syncthreads();
        {
          int j = tid >> 4, ksv = tid & 15;
          float a = 0.f;
          if (j < 30) {
            const f16* wr = &wk[j*520 + ksv*32];
            const f16* hr = &h1h[ksv*32];
            #pragma unroll
            for (int c = 0; c < 4; ++c) {
              f16x8 q = *(const f16x8*)(wr + c*8);
              f16x8 h = *(const f16x8*)(hr + c*8);
              #pragma unroll
              for (int e = 0; e < 8; ++e) a += (float)q[e] * (float)h[e];
            }
          }
          a += __shfl_xor(a, 1); a += __shfl_xor(a, 2);
          a += __shfl_xor(a, 4); a += __shfl_xor(a, 8);
          if (j < 30 && ksv == 0) skg[j] = a + bk[j];
        }
        __syncthreads();
        if (tid < 10) {
          sal[tid] = expf(skg[tid]);
          sbe[tid] = expf(skg[10+tid]);
          kap[tid] += expf(skg[20+tid]);
        }
        __syncthreads();
        if (tid < 64) {
          float u = (float)tid, ph = 0.f;
          #pragma unroll
          for (int k2 = 0; k2 < 10; ++k2) {
            float d = kap[k2] - u;
            ph += sal[k2]*expf(-sbe[k2]*d*d);
          }
          sphi[tid] = ph;
        }
        __syncthreads();
        if (tid < 54) {
          float wvv = 0.f;
          #pragma unroll 8
          for (int u = 0; u < 64; ++u) wvv += sphi[u]*cv[u*54 + tid];
          wtmp[tid] = wvv;
        }
        __syncthreads();
        if (tid < 27) {
          HU a, bu; a.h = (f16)wtmp[2*tid]; bu.h = (f16)wtmp[2*tid+1];
          cst32(AnxtW + ((b*1088 + 4 + 2*tid) >> 1), (unsigned)a.u | ((unsigned)bu.u << 16));
        } else if (tid == 27) {
          HU a, bu; a.h = (f16)xl[i*3+0]; bu.h = (f16)xl[i*3+1];
          cst32(AnxtW + ((b*1088 + 58) >> 1), (unsigned)a.u | ((unsigned)bu.u << 16));
        } else if (tid == 28) {
          HU a; a.h = (f16)xl[i*3+2];
          cst32(AnxtW + ((b*1088 + 60) >> 1), (unsigned)a.u);
        } else if (tid == 29 && i <= 598) {
          HU a, bu; a.h = (f16)xl[(i+1)*3+0]; bu.h = (f16)xl[(i+1)*3+1];
          cst32(AnxtW + ((b*1088) >> 1), (unsigned)a.u | ((unsigned)bu.u << 16));
        } else if (tid == 30 && i <= 598) {
          HU a; a.h = (f16)xl[(i+1)*3+2];
          cst32(AnxtW + ((b*1088 + 2) >> 1), (unsigned)a.u);
        }
      }
      if (i >= 2) {
        if (tid < 121) {
          unsigned uu = cld32u((unsigned*)outg + b*128 + tid);
          asm volatile("s_waitcnt vmcnt(0)" ::: "memory");
          float v; __builtin_memcpy(&v, &uu, 4);
          so[tid] = v;
        }
        __syncthreads();
        if (tid < 32) {
          float v = mix_loss(so, yl, i-2, tid);
          if (tid == 0) lreg += v;
        }
      }
    }
    gbar(flags, 3 + 2*i);
  }

  if (blk >= 96 && tid == 0) {
    unsigned uu; __builtin_memcpy(&uu, &lreg, 4);
    cst32((unsigned*)lossg + (blk - 96), uu);
  }
  gbar(flags, 1206);
  if (blk == 96 && tid < 64) {
    unsigned uu = cld32u((unsigned*)lossg + tid);
    asm volatile("s_waitcnt vmcnt(0)" ::: "memory");
    float v; __builtin_memcpy(&v, &uu, 4);
    #pragma unroll
    for (int d = 32; d >= 1; d >>= 1) v += __shfl_xor(v, d);
    if (tid == 0) out[0] = v / 38400.f;
  }
}

extern "C" void kernel_launch(void* const* d_in, const int* in_sizes, int n_in,
                              void* d_out, int out_size, void* d_ws, size_t ws_size,
                              hipStream_t stream)
{
  (void)in_sizes; (void)n_in; (void)out_size; (void)ws_size;
  const float* x    = (const float*)d_in[0];
  const float* y    = (const float*)d_in[1];
  const float* cvec = (const float*)d_in[2];
  const float* Wih1 = (const float*)d_in[3];
  const float* Whh1 = (const float*)d_in[4];
  const float* bih1 = (const float*)d_in[5];
  const float* bhh1 = (const float*)d_in[6];
  const float* Wih2 = (const float*)d_in[7];
  const float* Whh2 = (const float*)d_in[8];
  const float* bih2 = (const float*)d_in[9];
  const float* bhh2 = (const float*)d_in[10];
  const float* Wk   = (const float*)d_in[11];
  const float* bk   = (const float*)d_in[12];
  const float* Wo   = (const float*)d_in[13];
  const float* bo   = (const float*)d_in[14];
  float* out = (float*)d_out;
  float* wsf = (float*)d_ws;

  hipFuncSetAttribute((const void*)kmain, hipFuncAttributeMaxDynamicSharedMemorySize, DYN_LDS);

  k_init<<<256, 256, 0, stream>>>(wsf);

  void* args[] = {
    (void*)&x, (void*)&y, (void*)&cvec,
    (void*)&Wih1, (void*)&Whh1, (void*)&bih1, (void*)&bhh1,
    (void*)&Wih2, (void*)&Whh2, (void*)&bih2, (void*)&bhh2,
    (void*)&Wk, (void*)&bk, (void*)&Wo, (void*)&bo,
    (void*)&out, (void*)&wsf
  };
  hipLaunchCooperativeKernel((void*)kmain, dim3(NBLK), dim3(NT), args, DYN_LDS, stream);
}